// Round 13
// baseline (9063.863 us; speedup 1.0000x reference)
//
#include <hip/hip_runtime.h>
#include <math.h>

// B=4, DIM=192, H=W=64, L=4096, HEADS=6. f32 buffers; f64 routing chain (b=0).
// Heavy convs: LDS-staged 2-phase double-buffered pipeline (4-ch chunks),
// 4oc x 4px/thread, padded inputs. Epad uses stride-68 rows so exout's LDS
// reads stay 16B-aligned.

struct ExPtrs { const float* w[12]; const float* b[12]; };
struct DPtrs  { const float* wt[6]; const float* bias[6]; };

__device__ __forceinline__ void fma4(float4& a, float s, const float4& v) {
    a.x = fmaf(s, v.x, a.x); a.y = fmaf(s, v.y, a.y);
    a.z = fmaf(s, v.z, a.z); a.w = fmaf(s, v.w, a.w);
}

// ---------------- helpers ----------------
__global__ void zero_kernel(float* __restrict__ p, int n) {
    for (int i = blockIdx.x * 256 + threadIdx.x; i < n; i += gridDim.x * 256) p[i] = 0.f;
}

// I [4,192,64,64] -> Ipad [4,192,68,68] with 2-ring zero pad
__global__ void padfill_kernel(const float* __restrict__ I, float* __restrict__ Ipad) {
    const int n = 4 * 192 * 4624;
    for (int o = blockIdx.x * 256 + threadIdx.x; o < n; o += gridDim.x * 256) {
        int xx = o % 68;
        int t = o / 68;
        int yy = t % 68;
        int t2 = t / 68;
        int ch = t2 % 192;
        int b = t2 / 192;
        float v = 0.f;
        if (yy >= 2 && yy < 66 && xx >= 2 && xx < 66)
            v = I[(((size_t)(b * 192 + ch)) << 12) + (yy - 2) * 64 + (xx - 2)];
        Ipad[o] = v;
    }
}

// w[(og*4+u)*IC+ic][kk] -> wt[((og*IC+ic)*K2+kk)*4+u]
__global__ void wtr_kernel(const float* __restrict__ w, float* __restrict__ wt,
                           int OCg, int IC, int K2) {
    int n = OCg * IC * K2 * 4;
    for (int o = blockIdx.x * 256 + threadIdx.x; o < n; o += gridDim.x * 256) {
        int u = o & 3;
        int t = o >> 2;
        int kk = t % K2;
        int t2 = t / K2;
        int ic = t2 % IC;
        int og = t2 / IC;
        wt[o] = w[(((size_t)(og * 4 + u)) * IC + ic) * K2 + kk];
    }
}

// ================= routing chain, b=0, all f64 (unchanged) =================

__global__ void pool64_kernel(const float* __restrict__ T, double* __restrict__ xp) {
    int j = blockIdx.x;
    for (int l = threadIdx.x; l < 4096; l += 256) {
        const float* t = T + ((size_t)(4 * j)) * 4096 + l;
        double s = (double)t[0] + (double)t[4096] + (double)t[2 * 4096] + (double)t[3 * 4096];
        xp[(size_t)j * 4096 + l] = 0.25 * s;
    }
}

__global__ void norm64_f32_kernel(const float* __restrict__ src, double* __restrict__ dst) {
    size_t off = (size_t)blockIdx.x * 4096;
    double acc = 0.0;
    for (int i = threadIdx.x; i < 4096; i += 256) { double v = src[off + i]; acc += v * v; }
    __shared__ double red[256];
    red[threadIdx.x] = acc; __syncthreads();
    for (int st = 128; st > 0; st >>= 1) {
        if (threadIdx.x < st) red[threadIdx.x] += red[threadIdx.x + st];
        __syncthreads();
    }
    double scale = 1.0 / fmax(sqrt(red[0]), 1e-12);
    for (int i = threadIdx.x; i < 4096; i += 256) dst[off + i] = src[off + i] * scale;
}

__global__ void norm64_f64_kernel(double* __restrict__ buf) {
    size_t off = (size_t)blockIdx.x * 4096;
    double acc = 0.0;
    for (int i = threadIdx.x; i < 4096; i += 256) { double v = buf[off + i]; acc += v * v; }
    __shared__ double red[256];
    red[threadIdx.x] = acc; __syncthreads();
    for (int st = 128; st > 0; st >>= 1) {
        if (threadIdx.x < st) red[threadIdx.x] += red[threadIdx.x + st];
        __syncthreads();
    }
    double scale = 1.0 / fmax(sqrt(red[0]), 1e-12);
    for (int i = threadIdx.x; i < 4096; i += 256) buf[off + i] *= scale;
}

__global__ void attnA64_kernel(const double* __restrict__ qn, const double* __restrict__ kn,
                               double* __restrict__ A) {
    int hh = blockIdx.x;
    int t = threadIdx.x;
    int c = t >> 3, d = t & 7;
    const double* q = qn + ((size_t)(hh * 32 + c)) * 4096;
    const double* k = kn + ((size_t)(hh * 8 + d)) * 4096;
    double acc = 0.0;
    for (int i = 0; i < 4096; ++i) acc += q[i] * k[i];
    __shared__ double S[32][8];
    S[c][d] = acc;
    __syncthreads();
    if (t < 32) {
        double mx = -1e300;
        for (int j = 0; j < 8; ++j) mx = fmax(mx, S[t][j]);
        double e[8], sum = 0.0;
        for (int j = 0; j < 8; ++j) { e[j] = exp(S[t][j] - mx); sum += e[j]; }
        double inv = 1.0 / sum;
        for (int j = 0; j < 8; ++j) A[((size_t)(hh * 32 + t)) * 8 + j] = e[j] * inv;
    }
}

__global__ void aout64_kernel(const double* __restrict__ A, const double* __restrict__ kn,
                              double* __restrict__ out) {
    int l = blockIdx.x * 256 + threadIdx.x;
    int ch = blockIdx.y;
    int hh = ch >> 5;
    const double* a = A + (size_t)ch * 8;
    const double* v = kn + ((size_t)(hh * 8)) * 4096 + l;
    double acc = 0.0;
    #pragma unroll
    for (int d = 0; d < 8; ++d) acc += a[d] * v[(size_t)d * 4096];
    out[(size_t)ch * 4096 + l] = acc;
}

__global__ void fm64_kernel(const double* __restrict__ in, const float* __restrict__ w,
                            double* __restrict__ out) {
    int l = blockIdx.x * 256 + threadIdx.x;
    int oc = blockIdx.y;
    const double* src = in + l;
    const float* wr = w + (size_t)oc * 192;
    double acc = 0.0;
    for (int ic = 0; ic < 192; ++ic) acc += (double)wr[ic] * src[(size_t)ic * 4096];
    out[(size_t)oc * 4096 + l] = acc;
}

__global__ void meanx64_kernel(const double* __restrict__ fm, double* __restrict__ m) {
    int x = blockIdx.x;
    double acc = 0.0;
    for (int t = threadIdx.x; t < 192 * 64; t += 256) {
        int c = t >> 6, y = t & 63;
        acc += fm[(size_t)c * 4096 + y * 64 + x];
    }
    __shared__ double red[256];
    red[threadIdx.x] = acc; __syncthreads();
    for (int st = 128; st > 0; st >>= 1) {
        if (threadIdx.x < st) red[threadIdx.x] += red[threadIdx.x + st];
        __syncthreads();
    }
    if (threadIdx.x == 0) m[x] = red[0] / (192.0 * 64.0);
}

__global__ void route64_kernel(const double* __restrict__ m, int* __restrict__ idx) {
    if (threadIdx.x != 0) return;
    double bins[12];
    for (int i = 0; i < 12; ++i) {
        int st = (i * 64) / 12;
        int en = ((i + 1) * 64 + 11) / 12;   // ceil
        double s = 0.0;
        for (int j = st; j < en; ++j) s += m[j];
        bins[i] = s / (double)(en - st);
    }
    bool used[12] = {};
    for (int s = 0; s < 4; ++s) {
        int best = 0; double bv = -1e300;
        for (int j = 0; j < 12; ++j)
            if (!used[j] && bins[j] > bv) { best = j; bv = bins[j]; }
        used[best] = true;
        idx[s] = best;
    }
}

// ================= f32 compute kernels =================

__global__ void rownorm_kernel(const float* __restrict__ src, float* __restrict__ dst) {
    size_t off = (size_t)blockIdx.x * 4096;
    const float* s = src + off;
    float acc = 0.f;
    for (int i = threadIdx.x; i < 4096; i += 256) { float v = s[i]; acc += v * v; }
    __shared__ float red[256];
    red[threadIdx.x] = acc; __syncthreads();
    for (int st = 128; st > 0; st >>= 1) {
        if (threadIdx.x < st) red[threadIdx.x] += red[threadIdx.x + st];
        __syncthreads();
    }
    float scale = 1.0f / fmaxf(sqrtf(red[0]), 1e-12f);
    float* d = dst + off;
    for (int i = threadIdx.x; i < 4096; i += 256) d[i] = s[i] * scale;
}

// ---- dense LDS body: 4oc x 4px, 4-ch chunks double-buffered through LDS ----
// Ipad stride 68, channel 4624. Epad stride 68, channel 4488 (66 rows).
template<int KK>
__device__ __forceinline__ void dense_lds_body(const float* __restrict__ Ipad,
        const float* __restrict__ wt, const float* __restrict__ bias,
        float* __restrict__ Epad, float* __restrict__ sb,
        int b, int og, int tile, int tid) {
    constexpr int P    = (KK - 1) / 2;
    constexpr int K2   = KK * KK;
    constexpr int ROWS = 16 + KK - 1;
    constexpr int CPF  = ROWS * 68;          // floats per channel in LDS
    constexpr int NF4  = CPF;                // float4 per 4-ch chunk (4*CPF/4)
    constexpr int NIT  = (NF4 + 255) / 256;
    constexpr int OFF  = 2 - P;              // window index offset in win[8]
    int xq = tid & 15, ry = tid >> 4;
    int y0 = tile * 16, x0 = xq * 4;
    float4 acc[4];
    #pragma unroll
    for (int u = 0; u < 4; ++u) { float bv = bias[og * 4 + u]; acc[u] = make_float4(bv, bv, bv, bv); }
    const float* gch = Ipad + (size_t)b * 192 * 4624 + (size_t)(y0 + 2 - P) * 68;
    const float* wpo = wt + (size_t)og * 192 * K2 * 4;
    float4 sreg[NIT];
    #pragma unroll
    for (int i = 0; i < NIT; ++i) { int f = tid + i * 256; if (f < NF4) {
        int ch = f / (CPF / 4); int r4 = f - ch * (CPF / 4);
        sreg[i] = *(const float4*)(gch + (size_t)ch * 4624 + r4 * 4); } }
    #pragma unroll
    for (int i = 0; i < NIT; ++i) { int f = tid + i * 256; if (f < NF4) {
        int ch = f / (CPF / 4); int r4 = f - ch * (CPF / 4);
        *(float4*)(sb + ch * CPF + r4 * 4) = sreg[i]; } }
    for (int c = 0; c < 48; ++c) {
        __syncthreads();
        int half = c & 1;
        if (c + 1 < 48) {
            const float* g2 = gch + (size_t)(c + 1) * 4 * 4624;
            #pragma unroll
            for (int i = 0; i < NIT; ++i) { int f = tid + i * 256; if (f < NF4) {
                int ch = f / (CPF / 4); int r4 = f - ch * (CPF / 4);
                sreg[i] = *(const float4*)(g2 + (size_t)ch * 4624 + r4 * 4); } }
        }
        const float* lb = sb + half * 4 * CPF;
        const float* wc = wpo + (size_t)c * 4 * K2 * 4;
        #pragma unroll
        for (int ch = 0; ch < 4; ++ch) {
            const float* lch = lb + ch * CPF + ry * 68 + x0;
            const float* wq = wc + ch * K2 * 4;
            #pragma unroll
            for (int ky = 0; ky < KK; ++ky) {
                float4 A  = *(const float4*)(lch + ky * 68);
                float4 B2 = *(const float4*)(lch + ky * 68 + 4);
                float win[8] = {A.x, A.y, A.z, A.w, B2.x, B2.y, B2.z, B2.w};
                #pragma unroll
                for (int kx = 0; kx < KK; ++kx) {
                    float4 wv = *(const float4*)(wq + (ky * KK + kx) * 4);
                    float4 xv = make_float4(win[kx + OFF], win[kx + OFF + 1],
                                            win[kx + OFF + 2], win[kx + OFF + 3]);
                    fma4(acc[0], wv.x, xv); fma4(acc[1], wv.y, xv);
                    fma4(acc[2], wv.z, xv); fma4(acc[3], wv.w, xv);
                }
            }
        }
        if (c + 1 < 48) {
            float* ldst = sb + ((c + 1) & 1) * 4 * CPF;
            #pragma unroll
            for (int i = 0; i < NIT; ++i) { int f = tid + i * 256; if (f < NF4) {
                int ch = f / (CPF / 4); int r4 = f - ch * (CPF / 4);
                *(float4*)(ldst + ch * CPF + r4 * 4) = sreg[i]; } }
        }
    }
    int y = y0 + ry;
    float* dst = Epad + (size_t)(b * 192 + og * 4) * 4488 + (size_t)(y + 1) * 68 + (x0 + 1);
    #pragma unroll
    for (int u = 0; u < 4; ++u) {
        dst[(size_t)u * 4488 + 0] = acc[u].x;
        dst[(size_t)u * 4488 + 1] = acc[u].y;
        dst[(size_t)u * 4488 + 2] = acc[u].z;
        dst[(size_t)u * 4488 + 3] = acc[u].w;
    }
}

// ---- depthwise body on padded input: 4ch x 4px (no LDS) ----
template<int KK>
__device__ __forceinline__ void dw_body(const float* __restrict__ Ipad,
                                        const float* __restrict__ w,
                                        const float* __restrict__ bias,
                                        float* __restrict__ Epad,
                                        int b, int og, int tile, int tid) {
    constexpr int P = (KK - 1) / 2;
    int xq = tid & 15, ry = tid >> 4;
    int y = tile * 16 + ry, x0 = xq * 4;
    #pragma unroll
    for (int u = 0; u < 4; ++u) {
        int ch = og * 4 + u;
        float bv = bias[ch];
        float4 acc = make_float4(bv, bv, bv, bv);
        const float* rp = Ipad + (size_t)(b * 192 + ch) * 4624 + (y - P + 2) * 68 + (x0 - P + 2);
        #pragma unroll
        for (int ky = 0; ky < KK; ++ky) {
            float win[8];
            float4 A = *(const float4*)(rp + ky * 68);
            win[0] = A.x; win[1] = A.y; win[2] = A.z; win[3] = A.w;
            if constexpr (KK > 1) {
                float4 Bv = *(const float4*)(rp + ky * 68 + 4);
                win[4] = Bv.x; win[5] = Bv.y; win[6] = Bv.z; win[7] = Bv.w;
            } else { win[4] = win[5] = win[6] = win[7] = 0.f; }
            #pragma unroll
            for (int kx = 0; kx < KK; ++kx) {
                float wv = w[((size_t)ch * KK + ky) * KK + kx];
                float4 xv = make_float4(win[kx], win[kx + 1], win[kx + 2], win[kx + 3]);
                fma4(acc, wv, xv);
            }
        }
        float* dst = Epad + (size_t)(b * 192 + ch) * 4488 + (size_t)(y + 1) * 68 + (x0 + 1);
        dst[0] = acc.x; dst[1] = acc.y; dst[2] = acc.z; dst[3] = acc.w;
    }
}

// One dispatch per slot: runtime j -> templated body. grid (4, 48, 4), 256 thr.
__global__ void __launch_bounds__(256, 2)
expert_any_kernel(const float* __restrict__ Ipad, DPtrs dp, ExPtrs ep,
                  const int* __restrict__ idx, int slot,
                  float* __restrict__ Epad) {
    __shared__ float sb[10880];   // 2 halves x 4 ch x 20 rows x 68 (K=5 worst case)
    int j = idx[slot];
    j = j < 0 ? 0 : (j > 11 ? 11 : j);
    int tid = threadIdx.x, tile = blockIdx.x, og = blockIdx.y, b = blockIdx.z;
    int m = j % 3;
    if (j < 6) {
        const float* wt = dp.wt[j];
        const float* bias = dp.bias[j];
        if (m == 0) dense_lds_body<1>(Ipad, wt, bias, Epad, sb, b, og, tile, tid);
        else if (m == 1) dense_lds_body<3>(Ipad, wt, bias, Epad, sb, b, og, tile, tid);
        else dense_lds_body<5>(Ipad, wt, bias, Epad, sb, b, og, tile, tid);
    } else {
        const float* w = ep.w[j];
        const float* bias = ep.b[j];
        if (m == 0) dw_body<1>(Ipad, w, bias, Epad, b, og, tile, tid);
        else if (m == 1) dw_body<3>(Ipad, w, bias, Epad, b, og, tile, tid);
        else dw_body<5>(Ipad, w, bias, Epad, b, og, tile, tid);
    }
}

// exout slot accumulate (3x3 over Epad), LDS-staged like dense. grid (4, 48, 4).
__global__ void __launch_bounds__(256, 2)
exout_lds_kernel(const float* __restrict__ Epad, const float* __restrict__ wt,
                 const float* __restrict__ bias, float* __restrict__ out,
                 int slot) {
    __shared__ float sb[9792];    // 2 x 4 x 18 rows x 68
    constexpr int CPF = 18 * 68;  // 1224
    constexpr int NF4 = CPF;
    constexpr int NIT = (NF4 + 255) / 256;  // 5
    int tid = threadIdx.x;
    int xq = tid & 15, ry = tid >> 4;
    int tile = blockIdx.x, og = blockIdx.y, b = blockIdx.z;
    int y0 = tile * 16, x0 = xq * 4;
    float* dst = out + ((size_t)(b * 192 + og * 4)) * 4096 + (y0 + ry) * 64 + x0;
    float4 acc[4];
    #pragma unroll
    for (int u = 0; u < 4; ++u) {
        if (slot == 0) { float bv = bias[og * 4 + u]; acc[u] = make_float4(bv, bv, bv, bv); }
        else acc[u] = *(const float4*)(dst + (size_t)u * 4096);
    }
    const float* gch = Epad + (size_t)b * 192 * 4488 + (size_t)y0 * 68;
    const float* wpo = wt + ((size_t)og * 768 + slot * 192) * 36;
    float4 sreg[NIT];
    #pragma unroll
    for (int i = 0; i < NIT; ++i) { int f = tid + i * 256; if (f < NF4) {
        int ch = f / (CPF / 4); int r4 = f - ch * (CPF / 4);
        sreg[i] = *(const float4*)(gch + (size_t)ch * 4488 + r4 * 4); } }
    #pragma unroll
    for (int i = 0; i < NIT; ++i) { int f = tid + i * 256; if (f < NF4) {
        int ch = f / (CPF / 4); int r4 = f - ch * (CPF / 4);
        *(float4*)(sb + ch * CPF + r4 * 4) = sreg[i]; } }
    for (int c = 0; c < 48; ++c) {
        __syncthreads();
        int half = c & 1;
        if (c + 1 < 48) {
            const float* g2 = gch + (size_t)(c + 1) * 4 * 4488;
            #pragma unroll
            for (int i = 0; i < NIT; ++i) { int f = tid + i * 256; if (f < NF4) {
                int ch = f / (CPF / 4); int r4 = f - ch * (CPF / 4);
                sreg[i] = *(const float4*)(g2 + (size_t)ch * 4488 + r4 * 4); } }
        }
        const float* lb = sb + half * 4 * CPF;
        const float* wc = wpo + (size_t)c * 4 * 36;
        #pragma unroll
        for (int ch = 0; ch < 4; ++ch) {
            const float* lch = lb + ch * CPF + ry * 68 + x0;
            const float* wq = wc + ch * 36;
            #pragma unroll
            for (int ky = 0; ky < 3; ++ky) {
                float4 A  = *(const float4*)(lch + ky * 68);
                float4 B2 = *(const float4*)(lch + ky * 68 + 4);
                float win[8] = {A.x, A.y, A.z, A.w, B2.x, B2.y, B2.z, B2.w};
                #pragma unroll
                for (int kx = 0; kx < 3; ++kx) {
                    float4 wv = *(const float4*)(wq + (ky * 3 + kx) * 4);
                    float4 xv = make_float4(win[kx], win[kx + 1], win[kx + 2], win[kx + 3]);
                    fma4(acc[0], wv.x, xv); fma4(acc[1], wv.y, xv);
                    fma4(acc[2], wv.z, xv); fma4(acc[3], wv.w, xv);
                }
            }
        }
        if (c + 1 < 48) {
            float* ldst = sb + ((c + 1) & 1) * 4 * CPF;
            #pragma unroll
            for (int i = 0; i < NIT; ++i) { int f = tid + i * 256; if (f < NF4) {
                int ch = f / (CPF / 4); int r4 = f - ch * (CPF / 4);
                *(float4*)(ldst + ch * CPF + r4 * 4) = sreg[i]; } }
        }
    }
    #pragma unroll
    for (int u = 0; u < 4; ++u)
        *(float4*)(dst + (size_t)u * 4096) = acc[u];
}

// 1x1 conv, ic unrolled x4. grid (4, 48, 4).
__global__ void __launch_bounds__(256, 2)
conv1x1_sw_kernel(const float* __restrict__ in, const float* __restrict__ wt,
                  float* __restrict__ out) {
    int tid = threadIdx.x;
    int xq = tid & 15, ry = tid >> 4;
    int tile = blockIdx.x, og = blockIdx.y, b = blockIdx.z;
    int p0 = tile * 1024 + ry * 64 + xq * 4;
    float4 acc[4] = {};
    const float* src = in + (size_t)b * 192 * 4096 + p0;
    const float* wp = wt + (size_t)og * 192 * 4;
    for (int ic = 0; ic < 192; ic += 4) {
        float4 xv0 = *(const float4*)(src + (size_t)ic * 4096);
        float4 xv1 = *(const float4*)(src + (size_t)(ic + 1) * 4096);
        float4 xv2 = *(const float4*)(src + (size_t)(ic + 2) * 4096);
        float4 xv3 = *(const float4*)(src + (size_t)(ic + 3) * 4096);
        float4 wv0 = *(const float4*)(wp + ic * 4);
        float4 wv1 = *(const float4*)(wp + (ic + 1) * 4);
        float4 wv2 = *(const float4*)(wp + (ic + 2) * 4);
        float4 wv3 = *(const float4*)(wp + (ic + 3) * 4);
        fma4(acc[0], wv0.x, xv0); fma4(acc[1], wv0.y, xv0);
        fma4(acc[2], wv0.z, xv0); fma4(acc[3], wv0.w, xv0);
        fma4(acc[0], wv1.x, xv1); fma4(acc[1], wv1.y, xv1);
        fma4(acc[2], wv1.z, xv1); fma4(acc[3], wv1.w, xv1);
        fma4(acc[0], wv2.x, xv2); fma4(acc[1], wv2.y, xv2);
        fma4(acc[2], wv2.z, xv2); fma4(acc[3], wv2.w, xv2);
        fma4(acc[0], wv3.x, xv3); fma4(acc[1], wv3.y, xv3);
        fma4(acc[2], wv3.z, xv3); fma4(acc[3], wv3.w, xv3);
    }
    float* dst = out + ((size_t)(b * 192 + og * 4)) * 4096 + p0;
    #pragma unroll
    for (int u = 0; u < 4; ++u)
        *(float4*)(dst + (size_t)u * 4096) = acc[u];
}

// depthwise 3x3 pad1 no bias; plain in/out; w pre-offset. grid (16,192,4)
__global__ void dwconv_kernel(const float* __restrict__ in, const float* __restrict__ w,
                              float* __restrict__ out) {
    int l = blockIdx.x * 256 + threadIdx.x;
    int ch = blockIdx.y, b = blockIdx.z;
    int y = l >> 6, x = l & 63;
    const float* src = in + ((size_t)(b * 192 + ch)) * 4096;
    const float* wk = w + ch * 9;
    float acc = 0.f;
    #pragma unroll
    for (int ky = 0; ky < 3; ++ky)
        #pragma unroll
        for (int kx = 0; kx < 3; ++kx) {
            int yy = y + ky - 1, xx = x + kx - 1;
            if (yy >= 0 && yy < 64 && xx >= 0 && xx < 64)
                acc += wk[ky * 3 + kx] * src[yy * 64 + xx];
        }
    out[((size_t)(b * 192 + ch)) * 4096 + l] = acc;
}

// Final attention logits+softmax, one block per q-row. grid (768), 256 thr.
__global__ void __launch_bounds__(256, 2)
attnF_row_kernel(const float* __restrict__ qn, const float* __restrict__ kn,
                 const float* __restrict__ temp, float* __restrict__ AF) {
    int row = blockIdx.x;            // ((b*6+hh)*32 + c)
    int hh = (row >> 5) % 6, b = row / 192;
    int tid = threadIdx.x;
    const float* q = qn + ((size_t)(b * 192) + (row % 192)) * 4096;
    const float* kb = kn + ((size_t)(b * 192 + hh * 32)) * 4096;
    float acc[32];
    #pragma unroll
    for (int d = 0; d < 32; ++d) acc[d] = 0.f;
    for (int i = tid; i < 4096; i += 256) {
        float qv = q[i];
        #pragma unroll
        for (int d = 0; d < 32; ++d) acc[d] += qv * kb[(size_t)d * 4096 + i];
    }
    #pragma unroll
    for (int d = 0; d < 32; ++d) {
        acc[d] += __shfl_xor(acc[d], 32);
        acc[d] += __shfl_xor(acc[d], 16);
        acc[d] += __shfl_xor(acc[d], 8);
        acc[d] += __shfl_xor(acc[d], 4);
        acc[d] += __shfl_xor(acc[d], 2);
        acc[d] += __shfl_xor(acc[d], 1);
    }
    __shared__ float red[4][32];
    int wid = tid >> 6, lane = tid & 63;
    if (lane == 0) {
        #pragma unroll
        for (int d = 0; d < 32; ++d) red[wid][d] = acc[d];
    }
    __syncthreads();
    if (tid < 32) {
        float s = red[0][tid] + red[1][tid] + red[2][tid] + red[3][tid];
        s *= temp[hh];
        float mx = s;
        mx = fmaxf(mx, __shfl_xor(mx, 16));
        mx = fmaxf(mx, __shfl_xor(mx, 8));
        mx = fmaxf(mx, __shfl_xor(mx, 4));
        mx = fmaxf(mx, __shfl_xor(mx, 2));
        mx = fmaxf(mx, __shfl_xor(mx, 1));
        float e = expf(s - mx);
        float sum = e;
        sum += __shfl_xor(sum, 16);
        sum += __shfl_xor(sum, 8);
        sum += __shfl_xor(sum, 4);
        sum += __shfl_xor(sum, 2);
        sum += __shfl_xor(sum, 1);
        AF[(size_t)row * 32 + tid] = e / sum;
    }
}

__global__ void attnF_out_kernel(const float* __restrict__ AF, const float* __restrict__ v,
                                 float* __restrict__ out) {
    int l = blockIdx.x * 256 + threadIdx.x;
    int ch = blockIdx.y, b = blockIdx.z;
    int hh = ch >> 5, c = ch & 31;
    const float* a = AF + ((size_t)((b * 6 + hh) * 32 + c)) * 32;
    const float* vp = v + ((size_t)(b * 192 + hh * 32)) * 4096 + l;
    float acc = 0.f;
    #pragma unroll
    for (int d = 0; d < 32; ++d) acc += a[d] * vp[(size_t)d * 4096];
    out[((size_t)(b * 192 + ch)) * 4096 + l] = acc;
}

// ---------------- launch ----------------
extern "C" void kernel_launch(void* const* d_in, const int* in_sizes, int n_in,
                              void* d_out, int out_size, void* d_ws, size_t ws_size,
                              hipStream_t stream) {
    const float* I    = (const float*)d_in[0];
    const float* T    = (const float*)d_in[1];
    const float* temp = (const float*)d_in[2];
    const float* ca1  = (const float*)d_in[3];
    const float* exow = (const float*)d_in[4];
    const float* exob = (const float*)d_in[5];
    const float* kvw  = (const float*)d_in[6];
    const float* kvdw = (const float*)d_in[7];
    const float* qdw  = (const float*)d_in[8];
    const float* projw= (const float*)d_in[9];
    ExPtrs ep;
    for (int j = 0; j < 12; ++j) {
        ep.w[j] = (const float*)d_in[10 + 2 * j];
        ep.b[j] = (const float*)d_in[11 + 2 * j];
    }

    // Arena (floats), total ~69.4 MB:
    float* ws   = (float*)d_ws;
    float* AF   = ws;                       // 24576
    int*   idxb = (int*)(ws + 24576);       // 4
    float* R0   = ws + 32768;               // 3,145,728
    float* R1   = R0 + 3145728;             // 3,145,728
    float* Ipad = R1 + 3145728;             // 3,551,232 (later: KN)
    float* Epad = Ipad + 3551232;           // 3,446,784 = 4*192*4488 (later: V)
    double* dsm = (double*)(Epad + 3446784);
    double* A64 = dsm;                      // 1536
    double* m64 = dsm + 1536;               // 64
    float* wtd  = (float*)(dsm + 1600);     // dense wt: 2,580,480
    size_t wtoff[6] = {0, 36864, 368640, 1290240, 1327104, 1658880};
    float* wtexo  = wtd + 2580480;          // 1,327,104
    float* wtkv   = wtexo + 1327104;        // 73,728
    float* wtproj = wtkv + 73728;           // 36,864
    double* xpool64 = (double*)R0;               // 196,608 d
    double* qn64    = (double*)(R0 + 393216);    // 786,432 d
    double* aout64  = (double*)R1;               // 786,432 d
    double* fm64    = (double*)(R1 + 1572864);   // 786,432 d
    float* KN = Ipad;
    float* V  = Epad;
    DPtrs dp;
    for (int j = 0; j < 6; ++j) { dp.wt[j] = wtd + wtoff[j]; dp.bias[j] = ep.b[j]; }
    float* out  = (float*)d_out;

    dim3 g(16, 192, 4), gs(4, 48, 4);

    // ---- weight transposes + input padding ----
    for (int j = 0; j < 6; ++j) {
        int KK = 1 + 2 * (j % 3);
        wtr_kernel<<<512, 256, 0, stream>>>(ep.w[j], wtd + wtoff[j], 48, 192, KK * KK);
    }
    wtr_kernel<<<1024, 256, 0, stream>>>(exow, wtexo, 48, 768, 9);
    wtr_kernel<<<256, 256, 0, stream>>>(kvw, wtkv, 96, 192, 1);
    wtr_kernel<<<256, 256, 0, stream>>>(projw, wtproj, 48, 192, 1);
    padfill_kernel<<<2048, 256, 0, stream>>>(I, Ipad);
    zero_kernel<<<2048, 256, 0, stream>>>(Epad, 3446784);

    // ---- Routing chain (b=0, f64) ----
    pool64_kernel<<<48, 256, 0, stream>>>(T, xpool64);
    norm64_f32_kernel<<<192, 256, 0, stream>>>(I, qn64);
    norm64_f64_kernel<<<48, 256, 0, stream>>>(xpool64);
    attnA64_kernel<<<6, 256, 0, stream>>>(qn64, xpool64, A64);
    aout64_kernel<<<dim3(16, 192), 256, 0, stream>>>(A64, xpool64, aout64);
    fm64_kernel<<<dim3(16, 192), 256, 0, stream>>>(aout64, ca1, fm64);
    meanx64_kernel<<<64, 256, 0, stream>>>(fm64, m64);
    route64_kernel<<<1, 64, 0, stream>>>(m64, idxb);

    // ---- Experts: E in Epad, fmap2 accumulates in R1 ----
    for (int s = 0; s < 4; ++s) {
        expert_any_kernel<<<gs, 256, 0, stream>>>(Ipad, dp, ep, idxb, s, Epad);
        exout_lds_kernel<<<gs, 256, 0, stream>>>(Epad, wtexo, exob, R1, s);
    }

    // ---- kv k-half (Ipad dead -> KN) ----
    conv1x1_sw_kernel<<<gs, 256, 0, stream>>>(R1, wtkv, R0);
    dwconv_kernel<<<g, 256, 0, stream>>>(R0, kvdw, KN);
    rownorm_kernel<<<768, 256, 0, stream>>>(KN, KN);             // kn
    // ---- q ----
    dwconv_kernel<<<g, 256, 0, stream>>>(R1, qdw, R0);
    rownorm_kernel<<<768, 256, 0, stream>>>(R0, R0);             // qn
    attnF_row_kernel<<<768, 256, 0, stream>>>(R0, KN, temp, AF);
    // ---- kv v-half (Epad dead -> V) ----
    conv1x1_sw_kernel<<<gs, 256, 0, stream>>>(R1, wtkv + 36864, R0);
    dwconv_kernel<<<g, 256, 0, stream>>>(R0, kvdw + 192 * 9, V);

    attnF_out_kernel<<<g, 256, 0, stream>>>(AF, V, R0);
    conv1x1_sw_kernel<<<gs, 256, 0, stream>>>(R0, wtproj, out);
}

// Round 14
// 2067.554 us; speedup vs baseline: 4.3839x; 4.3839x over previous
//
#include <hip/hip_runtime.h>
#include <math.h>

// B=4, DIM=192, H=W=64, L=4096, HEADS=6. f32 buffers; f64 routing chain (b=0).
// Round-10 structure (sliding-window reg-tiled convs, no LDS) + ic-split x2:
// grid (4,48,8), half=z>>2; half0 -> Epad (bias-seeded), half1 -> compact
// partial in R0; combine kernel adds. Doubles grid occupancy (3->6 blk/CU)
// without changing window-load-per-FMA ratio.

struct ExPtrs { const float* w[12]; const float* b[12]; };
struct DPtrs  { const float* wt[6]; const float* bias[6]; };

__device__ __forceinline__ void fma4(float4& a, float s, const float4& v) {
    a.x = fmaf(s, v.x, a.x); a.y = fmaf(s, v.y, a.y);
    a.z = fmaf(s, v.z, a.z); a.w = fmaf(s, v.w, a.w);
}

// ---------------- helpers ----------------
__global__ void zero_kernel(float* __restrict__ p, int n) {
    for (int i = blockIdx.x * 256 + threadIdx.x; i < n; i += gridDim.x * 256) p[i] = 0.f;
}

// I [4,192,64,64] -> Ipad [4,192,68,68] with 2-ring zero pad
__global__ void padfill_kernel(const float* __restrict__ I, float* __restrict__ Ipad) {
    const int n = 4 * 192 * 4624;
    for (int o = blockIdx.x * 256 + threadIdx.x; o < n; o += gridDim.x * 256) {
        int xx = o % 68;
        int t = o / 68;
        int yy = t % 68;
        int t2 = t / 68;
        int ch = t2 % 192;
        int b = t2 / 192;
        float v = 0.f;
        if (yy >= 2 && yy < 66 && xx >= 2 && xx < 66)
            v = I[(((size_t)(b * 192 + ch)) << 12) + (yy - 2) * 64 + (xx - 2)];
        Ipad[o] = v;
    }
}

// w[(og*4+u)*IC+ic][kk] -> wt[((og*IC+ic)*K2+kk)*4+u]
__global__ void wtr_kernel(const float* __restrict__ w, float* __restrict__ wt,
                           int OCg, int IC, int K2) {
    int n = OCg * IC * K2 * 4;
    for (int o = blockIdx.x * 256 + threadIdx.x; o < n; o += gridDim.x * 256) {
        int u = o & 3;
        int t = o >> 2;
        int kk = t % K2;
        int t2 = t / K2;
        int ic = t2 % IC;
        int og = t2 / IC;
        wt[o] = w[(((size_t)(og * 4 + u)) * IC + ic) * K2 + kk];
    }
}

// ================= routing chain, b=0, all f64 (unchanged) =================

__global__ void pool64_kernel(const float* __restrict__ T, double* __restrict__ xp) {
    int j = blockIdx.x;
    for (int l = threadIdx.x; l < 4096; l += 256) {
        const float* t = T + ((size_t)(4 * j)) * 4096 + l;
        double s = (double)t[0] + (double)t[4096] + (double)t[2 * 4096] + (double)t[3 * 4096];
        xp[(size_t)j * 4096 + l] = 0.25 * s;
    }
}

__global__ void norm64_f32_kernel(const float* __restrict__ src, double* __restrict__ dst) {
    size_t off = (size_t)blockIdx.x * 4096;
    double acc = 0.0;
    for (int i = threadIdx.x; i < 4096; i += 256) { double v = src[off + i]; acc += v * v; }
    __shared__ double red[256];
    red[threadIdx.x] = acc; __syncthreads();
    for (int st = 128; st > 0; st >>= 1) {
        if (threadIdx.x < st) red[threadIdx.x] += red[threadIdx.x + st];
        __syncthreads();
    }
    double scale = 1.0 / fmax(sqrt(red[0]), 1e-12);
    for (int i = threadIdx.x; i < 4096; i += 256) dst[off + i] = src[off + i] * scale;
}

__global__ void norm64_f64_kernel(double* __restrict__ buf) {
    size_t off = (size_t)blockIdx.x * 4096;
    double acc = 0.0;
    for (int i = threadIdx.x; i < 4096; i += 256) { double v = buf[off + i]; acc += v * v; }
    __shared__ double red[256];
    red[threadIdx.x] = acc; __syncthreads();
    for (int st = 128; st > 0; st >>= 1) {
        if (threadIdx.x < st) red[threadIdx.x] += red[threadIdx.x + st];
        __syncthreads();
    }
    double scale = 1.0 / fmax(sqrt(red[0]), 1e-12);
    for (int i = threadIdx.x; i < 4096; i += 256) buf[off + i] *= scale;
}

__global__ void attnA64_kernel(const double* __restrict__ qn, const double* __restrict__ kn,
                               double* __restrict__ A) {
    int hh = blockIdx.x;
    int t = threadIdx.x;
    int c = t >> 3, d = t & 7;
    const double* q = qn + ((size_t)(hh * 32 + c)) * 4096;
    const double* k = kn + ((size_t)(hh * 8 + d)) * 4096;
    double acc = 0.0;
    for (int i = 0; i < 4096; ++i) acc += q[i] * k[i];
    __shared__ double S[32][8];
    S[c][d] = acc;
    __syncthreads();
    if (t < 32) {
        double mx = -1e300;
        for (int j = 0; j < 8; ++j) mx = fmax(mx, S[t][j]);
        double e[8], sum = 0.0;
        for (int j = 0; j < 8; ++j) { e[j] = exp(S[t][j] - mx); sum += e[j]; }
        double inv = 1.0 / sum;
        for (int j = 0; j < 8; ++j) A[((size_t)(hh * 32 + t)) * 8 + j] = e[j] * inv;
    }
}

__global__ void aout64_kernel(const double* __restrict__ A, const double* __restrict__ kn,
                              double* __restrict__ out) {
    int l = blockIdx.x * 256 + threadIdx.x;
    int ch = blockIdx.y;
    int hh = ch >> 5;
    const double* a = A + (size_t)ch * 8;
    const double* v = kn + ((size_t)(hh * 8)) * 4096 + l;
    double acc = 0.0;
    #pragma unroll
    for (int d = 0; d < 8; ++d) acc += a[d] * v[(size_t)d * 4096];
    out[(size_t)ch * 4096 + l] = acc;
}

__global__ void fm64_kernel(const double* __restrict__ in, const float* __restrict__ w,
                            double* __restrict__ out) {
    int l = blockIdx.x * 256 + threadIdx.x;
    int oc = blockIdx.y;
    const double* src = in + l;
    const float* wr = w + (size_t)oc * 192;
    double acc = 0.0;
    for (int ic = 0; ic < 192; ++ic) acc += (double)wr[ic] * src[(size_t)ic * 4096];
    out[(size_t)oc * 4096 + l] = acc;
}

__global__ void meanx64_kernel(const double* __restrict__ fm, double* __restrict__ m) {
    int x = blockIdx.x;
    double acc = 0.0;
    for (int t = threadIdx.x; t < 192 * 64; t += 256) {
        int c = t >> 6, y = t & 63;
        acc += fm[(size_t)c * 4096 + y * 64 + x];
    }
    __shared__ double red[256];
    red[threadIdx.x] = acc; __syncthreads();
    for (int st = 128; st > 0; st >>= 1) {
        if (threadIdx.x < st) red[threadIdx.x] += red[threadIdx.x + st];
        __syncthreads();
    }
    if (threadIdx.x == 0) m[x] = red[0] / (192.0 * 64.0);
}

__global__ void route64_kernel(const double* __restrict__ m, int* __restrict__ idx) {
    if (threadIdx.x != 0) return;
    double bins[12];
    for (int i = 0; i < 12; ++i) {
        int st = (i * 64) / 12;
        int en = ((i + 1) * 64 + 11) / 12;   // ceil
        double s = 0.0;
        for (int j = st; j < en; ++j) s += m[j];
        bins[i] = s / (double)(en - st);
    }
    bool used[12] = {};
    for (int s = 0; s < 4; ++s) {
        int best = 0; double bv = -1e300;
        for (int j = 0; j < 12; ++j)
            if (!used[j] && bins[j] > bv) { best = j; bv = bins[j]; }
        used[best] = true;
        idx[s] = best;
    }
}

// ================= f32 compute kernels =================

__global__ void rownorm_kernel(const float* __restrict__ src, float* __restrict__ dst) {
    size_t off = (size_t)blockIdx.x * 4096;
    const float* s = src + off;
    float acc = 0.f;
    for (int i = threadIdx.x; i < 4096; i += 256) { float v = s[i]; acc += v * v; }
    __shared__ float red[256];
    red[threadIdx.x] = acc; __syncthreads();
    for (int st = 128; st > 0; st >>= 1) {
        if (threadIdx.x < st) red[threadIdx.x] += red[threadIdx.x + st];
        __syncthreads();
    }
    float scale = 1.0f / fmaxf(sqrtf(red[0]), 1e-12f);
    float* d = dst + off;
    for (int i = threadIdx.x; i < 4096; i += 256) d[i] = s[i] * scale;
}

// Dense expert, sliding window, ic-split x2. grid (4, 48, 8), 256 thr.
// half0: ic 0..95, seed bias, write Epad (padded). half1: ic 96..191, write P1 compact.
template<int KK>
__global__ void dense_sw_kernel(const float* __restrict__ Ipad, DPtrs dp,
                                const int* __restrict__ idx, int slot,
                                float* __restrict__ Epad, float* __restrict__ P1) {
    int j = idx[slot];
    j = j < 0 ? 0 : (j > 11 ? 11 : j);
    if (j >= 6 || (1 + 2 * (j % 3)) != KK) return;
    constexpr int P = (KK - 1) / 2;
    constexpr int K2 = KK * KK;
    const float* wt = dp.wt[j];
    const float* bias = dp.bias[j];
    int tid = threadIdx.x;
    int xq = tid & 15, ry = tid >> 4;
    int tile = blockIdx.x, og = blockIdx.y;
    int b = blockIdx.z & 3, half = blockIdx.z >> 2;
    int y = tile * 16 + ry, x0 = xq * 4;
    float4 acc[4];
    #pragma unroll
    for (int u = 0; u < 4; ++u) {
        float bv = half ? 0.f : bias[og * 4 + u];
        acc[u] = make_float4(bv, bv, bv, bv);
    }
    const float* srcb = Ipad + (size_t)b * 192 * 4624 + (y - P + 2) * 68 + (x0 - P + 2);
    const float* wp = wt + (size_t)og * 192 * K2 * 4;
    int ic0 = half * 96;
    for (int ic = ic0; ic < ic0 + 96; ++ic) {
        const float* rp = srcb + (size_t)ic * 4624;
        const float* wq = wp + (size_t)ic * K2 * 4;
        #pragma unroll
        for (int ky = 0; ky < KK; ++ky) {
            float win[8];
            float4 A = *(const float4*)(rp + ky * 68);
            win[0] = A.x; win[1] = A.y; win[2] = A.z; win[3] = A.w;
            if (KK > 1) {
                float4 Bv = *(const float4*)(rp + ky * 68 + 4);
                win[4] = Bv.x; win[5] = Bv.y; win[6] = Bv.z; win[7] = Bv.w;
            } else {
                win[4] = win[5] = win[6] = win[7] = 0.f;
            }
            #pragma unroll
            for (int kx = 0; kx < KK; ++kx) {
                float4 wv = *(const float4*)(wq + (ky * KK + kx) * 4);
                float4 xv = make_float4(win[kx], win[kx + 1], win[kx + 2], win[kx + 3]);
                fma4(acc[0], wv.x, xv);
                fma4(acc[1], wv.y, xv);
                fma4(acc[2], wv.z, xv);
                fma4(acc[3], wv.w, xv);
            }
        }
    }
    if (half == 0) {
        float* dst = Epad + ((size_t)(b * 192 + og * 4)) * 4356 + (y + 1) * 66 + (x0 + 1);
        #pragma unroll
        for (int u = 0; u < 4; ++u)
            *(float4*)(dst + (size_t)u * 4356) = acc[u];
    } else {
        float* dst = P1 + ((size_t)(b * 192 + og * 4)) * 4096 + y * 64 + x0;
        #pragma unroll
        for (int u = 0; u < 4; ++u)
            *(float4*)(dst + (size_t)u * 4096) = acc[u];
    }
}

// Epad += P1 (compact), only for dense slots. grid (16, 192, 4).
__global__ void dense_combine_kernel(const int* __restrict__ idx, int slot,
                                     const float* __restrict__ P1,
                                     float* __restrict__ Epad) {
    int j = idx[slot];
    j = j < 0 ? 0 : (j > 11 ? 11 : j);
    if (j >= 6) return;
    int l = blockIdx.x * 256 + threadIdx.x;
    int ch = blockIdx.y, b = blockIdx.z;
    int y = l >> 6, x = l & 63;
    size_t pe = ((size_t)(b * 192 + ch)) * 4356 + (y + 1) * 66 + (x + 1);
    Epad[pe] += P1[((size_t)(b * 192 + ch)) * 4096 + l];
}

// Depthwise expert -> Epad. grid (16, 192, 4). (unchanged r10)
__global__ void expert_dw_kernel(const float* __restrict__ I, ExPtrs ep,
                                 const int* __restrict__ idx, int slot,
                                 float* __restrict__ Epad) {
    int j = idx[slot];
    j = j < 0 ? 0 : (j > 11 ? 11 : j);
    if (j < 6) return;
    int K = 1 + 2 * (j % 3), pad = j % 3;
    const float* w = ep.w[j];
    const float* bias = ep.b[j];
    int l = blockIdx.x * 256 + threadIdx.x;
    int ch = blockIdx.y, b = blockIdx.z;
    int y = l >> 6, x = l & 63;
    float acc = bias[ch];
    const float* src = I + ((size_t)(b * 192 + ch)) * 4096;
    for (int ky = 0; ky < K; ++ky)
        for (int kx = 0; kx < K; ++kx) {
            int yy = y + ky - pad, xx = x + kx - pad;
            if (yy >= 0 && yy < 64 && xx >= 0 && xx < 64)
                acc += w[((size_t)ch * K + ky) * K + kx] * src[yy * 64 + xx];
        }
    Epad[((size_t)(b * 192 + ch)) * 4356 + (y + 1) * 66 + (x + 1)] = acc;
}

// exout slot accumulate (3x3 over padded E), ic-split x2. grid (4, 48, 8).
// half0: slot-ic 0..95, RMW out (seed bias at slot0). half1: slot-ic 96..191 -> P1.
__global__ void exout_sw_kernel(const float* __restrict__ Epad, const float* __restrict__ wt,
                                const float* __restrict__ bias, float* __restrict__ out,
                                int slot, float* __restrict__ P1) {
    int tid = threadIdx.x;
    int xq = tid & 15, ry = tid >> 4;
    int tile = blockIdx.x, og = blockIdx.y;
    int b = blockIdx.z & 3, half = blockIdx.z >> 2;
    int y = tile * 16 + ry, x0 = xq * 4;
    float* dst = out + ((size_t)(b * 192 + og * 4)) * 4096 + y * 64 + x0;
    float* dstp = P1 + ((size_t)(b * 192 + og * 4)) * 4096 + y * 64 + x0;
    float4 acc[4];
    #pragma unroll
    for (int u = 0; u < 4; ++u) {
        if (half == 1) acc[u] = make_float4(0.f, 0.f, 0.f, 0.f);
        else if (slot == 0) { float bv = bias[og * 4 + u]; acc[u] = make_float4(bv, bv, bv, bv); }
        else acc[u] = *(const float4*)(dst + (size_t)u * 4096);
    }
    const float* srcb = Epad + (size_t)b * 192 * 4356 + y * 66 + x0;
    const float* wp = wt + ((size_t)og * 768 + slot * 192) * 9 * 4;
    int ic0 = half * 96;
    for (int ic = ic0; ic < ic0 + 96; ++ic) {
        const float* rp = srcb + (size_t)ic * 4356;
        const float* wq = wp + (size_t)ic * 36;
        #pragma unroll
        for (int ky = 0; ky < 3; ++ky) {
            float4 A = *(const float4*)(rp + ky * 66);
            float4 Bv = *(const float4*)(rp + ky * 66 + 4);
            float win[8] = {A.x, A.y, A.z, A.w, Bv.x, Bv.y, Bv.z, Bv.w};
            #pragma unroll
            for (int kx = 0; kx < 3; ++kx) {
                float4 wv = *(const float4*)(wq + (ky * 3 + kx) * 4);
                float4 xv = make_float4(win[kx], win[kx + 1], win[kx + 2], win[kx + 3]);
                fma4(acc[0], wv.x, xv);
                fma4(acc[1], wv.y, xv);
                fma4(acc[2], wv.z, xv);
                fma4(acc[3], wv.w, xv);
            }
        }
    }
    float* o = (half == 0) ? dst : dstp;
    #pragma unroll
    for (int u = 0; u < 4; ++u)
        *(float4*)(o + (size_t)u * 4096) = acc[u];
}

// out += P1, both compact. grid (16, 192, 4).
__global__ void exout_combine_kernel(const float* __restrict__ P1, float* __restrict__ out) {
    int l = blockIdx.x * 256 + threadIdx.x;
    int ch = blockIdx.y, b = blockIdx.z;
    size_t o = ((size_t)(b * 192 + ch)) * 4096 + l;
    out[o] += P1[o];
}

// 1x1 conv, ic unrolled x4. grid (4, 48, 4). (unchanged r10)
__global__ void conv1x1_sw_kernel(const float* __restrict__ in, const float* __restrict__ wt,
                                  float* __restrict__ out) {
    int tid = threadIdx.x;
    int xq = tid & 15, ry = tid >> 4;
    int tile = blockIdx.x, og = blockIdx.y, b = blockIdx.z;
    int p0 = tile * 1024 + ry * 64 + xq * 4;
    float4 acc[4] = {};
    const float* src = in + (size_t)b * 192 * 4096 + p0;
    const float* wp = wt + (size_t)og * 192 * 4;
    for (int ic = 0; ic < 192; ic += 4) {
        float4 xv0 = *(const float4*)(src + (size_t)ic * 4096);
        float4 xv1 = *(const float4*)(src + (size_t)(ic + 1) * 4096);
        float4 xv2 = *(const float4*)(src + (size_t)(ic + 2) * 4096);
        float4 xv3 = *(const float4*)(src + (size_t)(ic + 3) * 4096);
        float4 wv0 = *(const float4*)(wp + ic * 4);
        float4 wv1 = *(const float4*)(wp + (ic + 1) * 4);
        float4 wv2 = *(const float4*)(wp + (ic + 2) * 4);
        float4 wv3 = *(const float4*)(wp + (ic + 3) * 4);
        fma4(acc[0], wv0.x, xv0); fma4(acc[1], wv0.y, xv0);
        fma4(acc[2], wv0.z, xv0); fma4(acc[3], wv0.w, xv0);
        fma4(acc[0], wv1.x, xv1); fma4(acc[1], wv1.y, xv1);
        fma4(acc[2], wv1.z, xv1); fma4(acc[3], wv1.w, xv1);
        fma4(acc[0], wv2.x, xv2); fma4(acc[1], wv2.y, xv2);
        fma4(acc[2], wv2.z, xv2); fma4(acc[3], wv2.w, xv2);
        fma4(acc[0], wv3.x, xv3); fma4(acc[1], wv3.y, xv3);
        fma4(acc[2], wv3.z, xv3); fma4(acc[3], wv3.w, xv3);
    }
    float* dst = out + ((size_t)(b * 192 + og * 4)) * 4096 + p0;
    #pragma unroll
    for (int u = 0; u < 4; ++u)
        *(float4*)(dst + (size_t)u * 4096) = acc[u];
}

// depthwise 3x3 pad1 no bias; plain in/out; w pre-offset. grid (16,192,4)
__global__ void dwconv_kernel(const float* __restrict__ in, const float* __restrict__ w,
                              float* __restrict__ out) {
    int l = blockIdx.x * 256 + threadIdx.x;
    int ch = blockIdx.y, b = blockIdx.z;
    int y = l >> 6, x = l & 63;
    const float* src = in + ((size_t)(b * 192 + ch)) * 4096;
    const float* wk = w + ch * 9;
    float acc = 0.f;
    #pragma unroll
    for (int ky = 0; ky < 3; ++ky)
        #pragma unroll
        for (int kx = 0; kx < 3; ++kx) {
            int yy = y + ky - 1, xx = x + kx - 1;
            if (yy >= 0 && yy < 64 && xx >= 0 && xx < 64)
                acc += wk[ky * 3 + kx] * src[yy * 64 + xx];
        }
    out[((size_t)(b * 192 + ch)) * 4096 + l] = acc;
}

// Final attention logits+softmax, one block per q-row. grid (768), 256 thr.
__global__ void attnF_row_kernel(const float* __restrict__ qn, const float* __restrict__ kn,
                                 const float* __restrict__ temp, float* __restrict__ AF) {
    int row = blockIdx.x;            // ((b*6+hh)*32 + c)
    int hh = (row >> 5) % 6, b = row / 192;
    int tid = threadIdx.x;
    const float* q = qn + ((size_t)(b * 192) + (row % 192)) * 4096;
    const float* kb = kn + ((size_t)(b * 192 + hh * 32)) * 4096;
    float acc[32];
    #pragma unroll
    for (int d = 0; d < 32; ++d) acc[d] = 0.f;
    for (int i = tid; i < 4096; i += 256) {
        float qv = q[i];
        #pragma unroll
        for (int d = 0; d < 32; ++d) acc[d] += qv * kb[(size_t)d * 4096 + i];
    }
    #pragma unroll
    for (int d = 0; d < 32; ++d) {
        acc[d] += __shfl_xor(acc[d], 32);
        acc[d] += __shfl_xor(acc[d], 16);
        acc[d] += __shfl_xor(acc[d], 8);
        acc[d] += __shfl_xor(acc[d], 4);
        acc[d] += __shfl_xor(acc[d], 2);
        acc[d] += __shfl_xor(acc[d], 1);
    }
    __shared__ float red[4][32];
    int wid = tid >> 6, lane = tid & 63;
    if (lane == 0) {
        #pragma unroll
        for (int d = 0; d < 32; ++d) red[wid][d] = acc[d];
    }
    __syncthreads();
    if (tid < 32) {
        float s = red[0][tid] + red[1][tid] + red[2][tid] + red[3][tid];
        s *= temp[hh];
        float mx = s;
        mx = fmaxf(mx, __shfl_xor(mx, 16));
        mx = fmaxf(mx, __shfl_xor(mx, 8));
        mx = fmaxf(mx, __shfl_xor(mx, 4));
        mx = fmaxf(mx, __shfl_xor(mx, 2));
        mx = fmaxf(mx, __shfl_xor(mx, 1));
        float e = expf(s - mx);
        float sum = e;
        sum += __shfl_xor(sum, 16);
        sum += __shfl_xor(sum, 8);
        sum += __shfl_xor(sum, 4);
        sum += __shfl_xor(sum, 2);
        sum += __shfl_xor(sum, 1);
        AF[(size_t)row * 32 + tid] = e / sum;
    }
}

__global__ void attnF_out_kernel(const float* __restrict__ AF, const float* __restrict__ v,
                                 float* __restrict__ out) {
    int l = blockIdx.x * 256 + threadIdx.x;
    int ch = blockIdx.y, b = blockIdx.z;
    int hh = ch >> 5, c = ch & 31;
    const float* a = AF + ((size_t)((b * 6 + hh) * 32 + c)) * 32;
    const float* vp = v + ((size_t)(b * 192 + hh * 32)) * 4096 + l;
    float acc = 0.f;
    #pragma unroll
    for (int d = 0; d < 32; ++d) acc += a[d] * vp[(size_t)d * 4096];
    out[((size_t)(b * 192 + ch)) * 4096 + l] = acc;
}

// ---------------- launch ----------------
extern "C" void kernel_launch(void* const* d_in, const int* in_sizes, int n_in,
                              void* d_out, int out_size, void* d_ws, size_t ws_size,
                              hipStream_t stream) {
    const float* I    = (const float*)d_in[0];
    const float* T    = (const float*)d_in[1];
    const float* temp = (const float*)d_in[2];
    const float* ca1  = (const float*)d_in[3];
    const float* exow = (const float*)d_in[4];
    const float* exob = (const float*)d_in[5];
    const float* kvw  = (const float*)d_in[6];
    const float* kvdw = (const float*)d_in[7];
    const float* qdw  = (const float*)d_in[8];
    const float* projw= (const float*)d_in[9];
    ExPtrs ep;
    for (int j = 0; j < 12; ++j) {
        ep.w[j] = (const float*)d_in[10 + 2 * j];
        ep.b[j] = (const float*)d_in[11 + 2 * j];
    }

    // Arena (floats), total ~69 MB (round-10 layout; Epad stride-66 = 4356/ch):
    float* ws   = (float*)d_ws;
    float* AF   = ws;                       // 24576
    int*   idxb = (int*)(ws + 24576);       // 4
    float* R0   = ws + 32768;               // 3,145,728 (= dense/exout partial P1 during experts)
    float* R1   = R0 + 3145728;             // 3,145,728
    float* Ipad = R1 + 3145728;             // 3,551,232 (later: KN)
    float* Epad = Ipad + 3551232;           // 3,345,408 = 4*192*4356 (later: V)
    double* dsm = (double*)(Epad + 3345408);
    double* A64 = dsm;                      // 1536
    double* m64 = dsm + 1536;               // 64
    float* wtd  = (float*)(dsm + 1600);     // dense wt: 2,580,480
    size_t wtoff[6] = {0, 36864, 368640, 1290240, 1327104, 1658880};
    float* wtexo  = wtd + 2580480;          // 1,327,104
    float* wtkv   = wtexo + 1327104;        // 73,728
    float* wtproj = wtkv + 73728;           // 36,864
    double* xpool64 = (double*)R0;               // 196,608 d
    double* qn64    = (double*)(R0 + 393216);    // 786,432 d
    double* aout64  = (double*)R1;               // 786,432 d
    double* fm64    = (double*)(R1 + 1572864);   // 786,432 d
    float* KN = Ipad;
    float* V  = Epad;
    float* P1 = R0;                         // partial buffer during expert phase
    DPtrs dp;
    for (int j = 0; j < 6; ++j) { dp.wt[j] = wtd + wtoff[j]; dp.bias[j] = ep.b[j]; }
    float* out  = (float*)d_out;

    dim3 g(16, 192, 4), gs(4, 48, 4), gsplit(4, 48, 8);

    // ---- weight transposes + input padding ----
    for (int j = 0; j < 6; ++j) {
        int KK = 1 + 2 * (j % 3);
        wtr_kernel<<<512, 256, 0, stream>>>(ep.w[j], wtd + wtoff[j], 48, 192, KK * KK);
    }
    wtr_kernel<<<1024, 256, 0, stream>>>(exow, wtexo, 48, 768, 9);
    wtr_kernel<<<256, 256, 0, stream>>>(kvw, wtkv, 96, 192, 1);
    wtr_kernel<<<256, 256, 0, stream>>>(projw, wtproj, 48, 192, 1);
    padfill_kernel<<<2048, 256, 0, stream>>>(I, Ipad);
    zero_kernel<<<2048, 256, 0, stream>>>(Epad, 3345408);

    // ---- Routing chain (b=0, f64) ----
    pool64_kernel<<<48, 256, 0, stream>>>(T, xpool64);
    norm64_f32_kernel<<<192, 256, 0, stream>>>(I, qn64);
    norm64_f64_kernel<<<48, 256, 0, stream>>>(xpool64);
    attnA64_kernel<<<6, 256, 0, stream>>>(qn64, xpool64, A64);
    aout64_kernel<<<dim3(16, 192), 256, 0, stream>>>(A64, xpool64, aout64);
    fm64_kernel<<<dim3(16, 192), 256, 0, stream>>>(aout64, ca1, fm64);
    meanx64_kernel<<<64, 256, 0, stream>>>(fm64, m64);
    route64_kernel<<<1, 64, 0, stream>>>(m64, idxb);

    // ---- Experts (ic-split x2): E in Epad, partials in P1(R0), fmap2 in R1 ----
    for (int s = 0; s < 4; ++s) {
        dense_sw_kernel<1><<<gsplit, 256, 0, stream>>>(Ipad, dp, idxb, s, Epad, P1);
        dense_sw_kernel<3><<<gsplit, 256, 0, stream>>>(Ipad, dp, idxb, s, Epad, P1);
        dense_sw_kernel<5><<<gsplit, 256, 0, stream>>>(Ipad, dp, idxb, s, Epad, P1);
        expert_dw_kernel<<<g, 256, 0, stream>>>(I, ep, idxb, s, Epad);
        dense_combine_kernel<<<g, 256, 0, stream>>>(idxb, s, P1, Epad);
        exout_sw_kernel<<<gsplit, 256, 0, stream>>>(Epad, wtexo, exob, R1, s, P1);
        exout_combine_kernel<<<g, 256, 0, stream>>>(P1, R1);
    }

    // ---- kv k-half (Ipad dead -> KN) ----
    conv1x1_sw_kernel<<<gs, 256, 0, stream>>>(R1, wtkv, R0);
    dwconv_kernel<<<g, 256, 0, stream>>>(R0, kvdw, KN);
    rownorm_kernel<<<768, 256, 0, stream>>>(KN, KN);             // kn
    // ---- q ----
    dwconv_kernel<<<g, 256, 0, stream>>>(R1, qdw, R0);
    rownorm_kernel<<<768, 256, 0, stream>>>(R0, R0);             // qn
    attnF_row_kernel<<<768, 256, 0, stream>>>(R0, KN, temp, AF);
    // ---- kv v-half (Epad dead -> V) ----
    conv1x1_sw_kernel<<<gs, 256, 0, stream>>>(R1, wtkv + 36864, R0);
    dwconv_kernel<<<g, 256, 0, stream>>>(R0, kvdw + 192 * 9, V);

    attnF_out_kernel<<<g, 256, 0, stream>>>(AF, V, R0);
    conv1x1_sw_kernel<<<gs, 256, 0, stream>>>(R0, wtproj, out);
}

// Round 15
// 1547.779 us; speedup vs baseline: 5.8560x; 1.3358x over previous
//
#include <hip/hip_runtime.h>
#include <math.h>

// B=4, DIM=192, H=W=64, L=4096, HEADS=6. f32 buffers; f64 routing chain (b=0).
// Convs: sliding-window reg-tiled, 8oc x 4px/thread (halves L1 bytes/FMA vs 4oc),
// padded inputs, ic-split x2 (grid (4,24,8)). Weights [og8][ic][kk][8] -> uniform
// s_loads. Stage-A f64 logits chunk-parallelized (6x16 blocks + ordered reduce).

struct ExPtrs { const float* w[12]; const float* b[12]; };
struct DPtrs  { const float* wt[6]; const float* bias[6]; };

__device__ __forceinline__ void fma4(float4& a, float s, const float4& v) {
    a.x = fmaf(s, v.x, a.x); a.y = fmaf(s, v.y, a.y);
    a.z = fmaf(s, v.z, a.z); a.w = fmaf(s, v.w, a.w);
}

// ---------------- helpers ----------------
__global__ void zero_kernel(float* __restrict__ p, int n) {
    for (int i = blockIdx.x * 256 + threadIdx.x; i < n; i += gridDim.x * 256) p[i] = 0.f;
}

// I [4,192,64,64] -> Ipad [4,192,68,68] with 2-ring zero pad
__global__ void padfill_kernel(const float* __restrict__ I, float* __restrict__ Ipad) {
    const int n = 4 * 192 * 4624;
    for (int o = blockIdx.x * 256 + threadIdx.x; o < n; o += gridDim.x * 256) {
        int xx = o % 68;
        int t = o / 68;
        int yy = t % 68;
        int t2 = t / 68;
        int ch = t2 % 192;
        int b = t2 / 192;
        float v = 0.f;
        if (yy >= 2 && yy < 66 && xx >= 2 && xx < 66)
            v = I[(((size_t)(b * 192 + ch)) << 12) + (yy - 2) * 64 + (xx - 2)];
        Ipad[o] = v;
    }
}

// w[((og*8+u)*IC+ic)*K2+kk] -> wt[(((og*IC+ic)*K2)+kk)*8+u]
__global__ void wtr8_kernel(const float* __restrict__ w, float* __restrict__ wt,
                            int OCg, int IC, int K2) {
    int n = OCg * IC * K2 * 8;
    for (int o = blockIdx.x * 256 + threadIdx.x; o < n; o += gridDim.x * 256) {
        int u = o & 7;
        int t = o >> 3;
        int kk = t % K2;
        int t2 = t / K2;
        int ic = t2 % IC;
        int og = t2 / IC;
        wt[o] = w[(((size_t)(og * 8 + u)) * IC + ic) * K2 + kk];
    }
}

// ================= routing chain, b=0, all f64 =================

__global__ void pool64_kernel(const float* __restrict__ T, double* __restrict__ xp) {
    int j = blockIdx.x;
    for (int l = threadIdx.x; l < 4096; l += 256) {
        const float* t = T + ((size_t)(4 * j)) * 4096 + l;
        double s = (double)t[0] + (double)t[4096] + (double)t[2 * 4096] + (double)t[3 * 4096];
        xp[(size_t)j * 4096 + l] = 0.25 * s;
    }
}

__global__ void norm64_f32_kernel(const float* __restrict__ src, double* __restrict__ dst) {
    size_t off = (size_t)blockIdx.x * 4096;
    double acc = 0.0;
    for (int i = threadIdx.x; i < 4096; i += 256) { double v = src[off + i]; acc += v * v; }
    __shared__ double red[256];
    red[threadIdx.x] = acc; __syncthreads();
    for (int st = 128; st > 0; st >>= 1) {
        if (threadIdx.x < st) red[threadIdx.x] += red[threadIdx.x + st];
        __syncthreads();
    }
    double scale = 1.0 / fmax(sqrt(red[0]), 1e-12);
    for (int i = threadIdx.x; i < 4096; i += 256) dst[off + i] = src[off + i] * scale;
}

__global__ void norm64_f64_kernel(double* __restrict__ buf) {
    size_t off = (size_t)blockIdx.x * 4096;
    double acc = 0.0;
    for (int i = threadIdx.x; i < 4096; i += 256) { double v = buf[off + i]; acc += v * v; }
    __shared__ double red[256];
    red[threadIdx.x] = acc; __syncthreads();
    for (int st = 128; st > 0; st >>= 1) {
        if (threadIdx.x < st) red[threadIdx.x] += red[threadIdx.x + st];
        __syncthreads();
    }
    double scale = 1.0 / fmax(sqrt(red[0]), 1e-12);
    for (int i = threadIdx.x; i < 4096; i += 256) buf[off + i] *= scale;
}

// Stage-A logits partials: grid (6, 16). PA[((hh*32+c)*8+d)*16+cc]
__global__ void attnA64p_kernel(const double* __restrict__ qn, const double* __restrict__ kn,
                                double* __restrict__ PA) {
    int hh = blockIdx.x, cc = blockIdx.y;
    int t = threadIdx.x;
    int c = t >> 3, d = t & 7;
    const double* q = qn + ((size_t)(hh * 32 + c)) * 4096 + cc * 256;
    const double* k = kn + ((size_t)(hh * 8 + d)) * 4096 + cc * 256;
    double acc = 0.0;
    for (int i = 0; i < 256; ++i) acc += q[i] * k[i];
    PA[((size_t)((hh * 32 + c) * 8 + d)) * 16 + cc] = acc;
}

// Reduce partials (ordered) + softmax over the 8 base logits. grid (6).
__global__ void attnA64r_kernel(const double* __restrict__ PA, double* __restrict__ A) {
    int hh = blockIdx.x;
    int t = threadIdx.x;
    int c = t >> 3, d = t & 7;
    double acc = 0.0;
    const double* p = PA + ((size_t)((hh * 32 + c) * 8 + d)) * 16;
    for (int cc = 0; cc < 16; ++cc) acc += p[cc];
    __shared__ double S[32][8];
    S[c][d] = acc;
    __syncthreads();
    if (t < 32) {
        double mx = -1e300;
        for (int j = 0; j < 8; ++j) mx = fmax(mx, S[t][j]);
        double e[8], sum = 0.0;
        for (int j = 0; j < 8; ++j) { e[j] = exp(S[t][j] - mx); sum += e[j]; }
        double inv = 1.0 / sum;
        for (int j = 0; j < 8; ++j) A[((size_t)(hh * 32 + t)) * 8 + j] = e[j] * inv;
    }
}

__global__ void aout64_kernel(const double* __restrict__ A, const double* __restrict__ kn,
                              double* __restrict__ out) {
    int l = blockIdx.x * 256 + threadIdx.x;
    int ch = blockIdx.y;
    int hh = ch >> 5;
    const double* a = A + (size_t)ch * 8;
    const double* v = kn + ((size_t)(hh * 8)) * 4096 + l;
    double acc = 0.0;
    #pragma unroll
    for (int d = 0; d < 8; ++d) acc += a[d] * v[(size_t)d * 4096];
    out[(size_t)ch * 4096 + l] = acc;
}

__global__ void fm64_kernel(const double* __restrict__ in, const float* __restrict__ w,
                            double* __restrict__ out) {
    int l = blockIdx.x * 256 + threadIdx.x;
    int oc = blockIdx.y;
    const double* src = in + l;
    const float* wr = w + (size_t)oc * 192;
    double acc = 0.0;
    for (int ic = 0; ic < 192; ++ic) acc += (double)wr[ic] * src[(size_t)ic * 4096];
    out[(size_t)oc * 4096 + l] = acc;
}

__global__ void meanx64_kernel(const double* __restrict__ fm, double* __restrict__ m) {
    int x = blockIdx.x;
    double acc = 0.0;
    for (int t = threadIdx.x; t < 192 * 64; t += 256) {
        int c = t >> 6, y = t & 63;
        acc += fm[(size_t)c * 4096 + y * 64 + x];
    }
    __shared__ double red[256];
    red[threadIdx.x] = acc; __syncthreads();
    for (int st = 128; st > 0; st >>= 1) {
        if (threadIdx.x < st) red[threadIdx.x] += red[threadIdx.x + st];
        __syncthreads();
    }
    if (threadIdx.x == 0) m[x] = red[0] / (192.0 * 64.0);
}

__global__ void route64_kernel(const double* __restrict__ m, int* __restrict__ idx) {
    if (threadIdx.x != 0) return;
    double bins[12];
    for (int i = 0; i < 12; ++i) {
        int st = (i * 64) / 12;
        int en = ((i + 1) * 64 + 11) / 12;   // ceil
        double s = 0.0;
        for (int j = st; j < en; ++j) s += m[j];
        bins[i] = s / (double)(en - st);
    }
    bool used[12] = {};
    for (int s = 0; s < 4; ++s) {
        int best = 0; double bv = -1e300;
        for (int j = 0; j < 12; ++j)
            if (!used[j] && bins[j] > bv) { best = j; bv = bins[j]; }
        used[best] = true;
        idx[s] = best;
    }
}

// ================= f32 compute kernels =================

__global__ void rownorm_kernel(const float* __restrict__ src, float* __restrict__ dst) {
    size_t off = (size_t)blockIdx.x * 4096;
    const float* s = src + off;
    float acc = 0.f;
    for (int i = threadIdx.x; i < 4096; i += 256) { float v = s[i]; acc += v * v; }
    __shared__ float red[256];
    red[threadIdx.x] = acc; __syncthreads();
    for (int st = 128; st > 0; st >>= 1) {
        if (threadIdx.x < st) red[threadIdx.x] += red[threadIdx.x + st];
        __syncthreads();
    }
    float scale = 1.0f / fmaxf(sqrtf(red[0]), 1e-12f);
    float* d = dst + off;
    for (int i = threadIdx.x; i < 4096; i += 256) d[i] = s[i] * scale;
}

// Dense expert, sliding window, 8oc x 4px, ic-split x2. grid (4, 24, 8), 256 thr.
template<int KK>
__global__ void dense_sw_kernel(const float* __restrict__ Ipad, DPtrs dp,
                                const int* __restrict__ idx, int slot,
                                float* __restrict__ Epad, float* __restrict__ P1) {
    int j = idx[slot];
    j = j < 0 ? 0 : (j > 11 ? 11 : j);
    if (j >= 6 || (1 + 2 * (j % 3)) != KK) return;
    constexpr int P = (KK - 1) / 2;
    constexpr int K2 = KK * KK;
    const float* wt = dp.wt[j];
    const float* bias = dp.bias[j];
    int tid = threadIdx.x;
    int xq = tid & 15, ry = tid >> 4;
    int tile = blockIdx.x, og = blockIdx.y;
    int b = blockIdx.z & 3, half = blockIdx.z >> 2;
    int y = tile * 16 + ry, x0 = xq * 4;
    float4 acc[8];
    #pragma unroll
    for (int u = 0; u < 8; ++u) {
        float bv = half ? 0.f : bias[og * 8 + u];
        acc[u] = make_float4(bv, bv, bv, bv);
    }
    const float* srcb = Ipad + (size_t)b * 192 * 4624 + (y - P + 2) * 68 + (x0 - P + 2);
    const float* wp = wt + (size_t)og * 192 * K2 * 8;
    int ic0 = half * 96;
    for (int ic = ic0; ic < ic0 + 96; ++ic) {
        const float* rp = srcb + (size_t)ic * 4624;
        const float* wq = wp + (size_t)ic * K2 * 8;
        #pragma unroll
        for (int ky = 0; ky < KK; ++ky) {
            float win[8];
            float4 A = *(const float4*)(rp + ky * 68);
            win[0] = A.x; win[1] = A.y; win[2] = A.z; win[3] = A.w;
            if (KK > 1) {
                float4 Bv = *(const float4*)(rp + ky * 68 + 4);
                win[4] = Bv.x; win[5] = Bv.y; win[6] = Bv.z; win[7] = Bv.w;
            } else {
                win[4] = win[5] = win[6] = win[7] = 0.f;
            }
            #pragma unroll
            for (int kx = 0; kx < KK; ++kx) {
                const float* wqq = wq + (ky * KK + kx) * 8;
                float4 wA = *(const float4*)(wqq);
                float4 wB = *(const float4*)(wqq + 4);
                float4 xv = make_float4(win[kx], win[kx + 1], win[kx + 2], win[kx + 3]);
                fma4(acc[0], wA.x, xv); fma4(acc[1], wA.y, xv);
                fma4(acc[2], wA.z, xv); fma4(acc[3], wA.w, xv);
                fma4(acc[4], wB.x, xv); fma4(acc[5], wB.y, xv);
                fma4(acc[6], wB.z, xv); fma4(acc[7], wB.w, xv);
            }
        }
    }
    if (half == 0) {
        float* dst = Epad + ((size_t)(b * 192 + og * 8)) * 4356 + (y + 1) * 66 + (x0 + 1);
        #pragma unroll
        for (int u = 0; u < 8; ++u)
            *(float4*)(dst + (size_t)u * 4356) = acc[u];
    } else {
        float* dst = P1 + ((size_t)(b * 192 + og * 8)) * 4096 + y * 64 + x0;
        #pragma unroll
        for (int u = 0; u < 8; ++u)
            *(float4*)(dst + (size_t)u * 4096) = acc[u];
    }
}

// Epad += P1 (compact), only for dense slots. grid (16, 192, 4).
__global__ void dense_combine_kernel(const int* __restrict__ idx, int slot,
                                     const float* __restrict__ P1,
                                     float* __restrict__ Epad) {
    int j = idx[slot];
    j = j < 0 ? 0 : (j > 11 ? 11 : j);
    if (j >= 6) return;
    int l = blockIdx.x * 256 + threadIdx.x;
    int ch = blockIdx.y, b = blockIdx.z;
    int y = l >> 6, x = l & 63;
    size_t pe = ((size_t)(b * 192 + ch)) * 4356 + (y + 1) * 66 + (x + 1);
    Epad[pe] += P1[((size_t)(b * 192 + ch)) * 4096 + l];
}

// Depthwise expert -> Epad. grid (16, 192, 4).
__global__ void expert_dw_kernel(const float* __restrict__ I, ExPtrs ep,
                                 const int* __restrict__ idx, int slot,
                                 float* __restrict__ Epad) {
    int j = idx[slot];
    j = j < 0 ? 0 : (j > 11 ? 11 : j);
    if (j < 6) return;
    int K = 1 + 2 * (j % 3), pad = j % 3;
    const float* w = ep.w[j];
    const float* bias = ep.b[j];
    int l = blockIdx.x * 256 + threadIdx.x;
    int ch = blockIdx.y, b = blockIdx.z;
    int y = l >> 6, x = l & 63;
    float acc = bias[ch];
    const float* src = I + ((size_t)(b * 192 + ch)) * 4096;
    for (int ky = 0; ky < K; ++ky)
        for (int kx = 0; kx < K; ++kx) {
            int yy = y + ky - pad, xx = x + kx - pad;
            if (yy >= 0 && yy < 64 && xx >= 0 && xx < 64)
                acc += w[((size_t)ch * K + ky) * K + kx] * src[yy * 64 + xx];
        }
    Epad[((size_t)(b * 192 + ch)) * 4356 + (y + 1) * 66 + (x + 1)] = acc;
}

// exout slot accumulate (3x3 over padded E), 8oc, ic-split x2. grid (4, 24, 8).
__global__ void exout_sw_kernel(const float* __restrict__ Epad, const float* __restrict__ wt,
                                const float* __restrict__ bias, float* __restrict__ out,
                                int slot, float* __restrict__ P1) {
    int tid = threadIdx.x;
    int xq = tid & 15, ry = tid >> 4;
    int tile = blockIdx.x, og = blockIdx.y;
    int b = blockIdx.z & 3, half = blockIdx.z >> 2;
    int y = tile * 16 + ry, x0 = xq * 4;
    float* dst = out + ((size_t)(b * 192 + og * 8)) * 4096 + y * 64 + x0;
    float* dstp = P1 + ((size_t)(b * 192 + og * 8)) * 4096 + y * 64 + x0;
    float4 acc[8];
    #pragma unroll
    for (int u = 0; u < 8; ++u) {
        if (half == 1) acc[u] = make_float4(0.f, 0.f, 0.f, 0.f);
        else if (slot == 0) { float bv = bias[og * 8 + u]; acc[u] = make_float4(bv, bv, bv, bv); }
        else acc[u] = *(const float4*)(dst + (size_t)u * 4096);
    }
    const float* srcb = Epad + (size_t)b * 192 * 4356 + y * 66 + x0;
    const float* wp = wt + ((size_t)og * 768 + slot * 192) * 72;
    int ic0 = half * 96;
    for (int ic = ic0; ic < ic0 + 96; ++ic) {
        const float* rp = srcb + (size_t)ic * 4356;
        const float* wq = wp + (size_t)ic * 72;
        #pragma unroll
        for (int ky = 0; ky < 3; ++ky) {
            float4 A = *(const float4*)(rp + ky * 66);
            float4 Bv = *(const float4*)(rp + ky * 66 + 4);
            float win[8] = {A.x, A.y, A.z, A.w, Bv.x, Bv.y, Bv.z, Bv.w};
            #pragma unroll
            for (int kx = 0; kx < 3; ++kx) {
                const float* wqq = wq + (ky * 3 + kx) * 8;
                float4 wA = *(const float4*)(wqq);
                float4 wB = *(const float4*)(wqq + 4);
                float4 xv = make_float4(win[kx], win[kx + 1], win[kx + 2], win[kx + 3]);
                fma4(acc[0], wA.x, xv); fma4(acc[1], wA.y, xv);
                fma4(acc[2], wA.z, xv); fma4(acc[3], wA.w, xv);
                fma4(acc[4], wB.x, xv); fma4(acc[5], wB.y, xv);
                fma4(acc[6], wB.z, xv); fma4(acc[7], wB.w, xv);
            }
        }
    }
    float* o = (half == 0) ? dst : dstp;
    #pragma unroll
    for (int u = 0; u < 8; ++u)
        *(float4*)(o + (size_t)u * 4096) = acc[u];
}

// out += P1, both compact. grid (16, 192, 4).
__global__ void exout_combine_kernel(const float* __restrict__ P1, float* __restrict__ out) {
    int l = blockIdx.x * 256 + threadIdx.x;
    int ch = blockIdx.y, b = blockIdx.z;
    size_t o = ((size_t)(b * 192 + ch)) * 4096 + l;
    out[o] += P1[o];
}

// 1x1 conv, 8oc. grid (4, 24, 4). wt pre-offset for oc-half.
__global__ void conv1x1_sw_kernel(const float* __restrict__ in, const float* __restrict__ wt,
                                  float* __restrict__ out) {
    int tid = threadIdx.x;
    int xq = tid & 15, ry = tid >> 4;
    int tile = blockIdx.x, og = blockIdx.y, b = blockIdx.z;
    int p0 = tile * 1024 + ry * 64 + xq * 4;
    float4 acc[8] = {};
    const float* src = in + (size_t)b * 192 * 4096 + p0;
    const float* wp = wt + (size_t)og * 192 * 8;
    for (int ic = 0; ic < 192; ic += 2) {
        float4 xv0 = *(const float4*)(src + (size_t)ic * 4096);
        float4 xv1 = *(const float4*)(src + (size_t)(ic + 1) * 4096);
        float4 wA0 = *(const float4*)(wp + ic * 8);
        float4 wB0 = *(const float4*)(wp + ic * 8 + 4);
        float4 wA1 = *(const float4*)(wp + ic * 8 + 8);
        float4 wB1 = *(const float4*)(wp + ic * 8 + 12);
        fma4(acc[0], wA0.x, xv0); fma4(acc[1], wA0.y, xv0);
        fma4(acc[2], wA0.z, xv0); fma4(acc[3], wA0.w, xv0);
        fma4(acc[4], wB0.x, xv0); fma4(acc[5], wB0.y, xv0);
        fma4(acc[6], wB0.z, xv0); fma4(acc[7], wB0.w, xv0);
        fma4(acc[0], wA1.x, xv1); fma4(acc[1], wA1.y, xv1);
        fma4(acc[2], wA1.z, xv1); fma4(acc[3], wA1.w, xv1);
        fma4(acc[4], wB1.x, xv1); fma4(acc[5], wB1.y, xv1);
        fma4(acc[6], wB1.z, xv1); fma4(acc[7], wB1.w, xv1);
    }
    float* dst = out + ((size_t)(b * 192 + og * 8)) * 4096 + p0;
    #pragma unroll
    for (int u = 0; u < 8; ++u)
        *(float4*)(dst + (size_t)u * 4096) = acc[u];
}

// depthwise 3x3 pad1 no bias; plain in/out; w pre-offset. grid (16,192,4)
__global__ void dwconv_kernel(const float* __restrict__ in, const float* __restrict__ w,
                              float* __restrict__ out) {
    int l = blockIdx.x * 256 + threadIdx.x;
    int ch = blockIdx.y, b = blockIdx.z;
    int y = l >> 6, x = l & 63;
    const float* src = in + ((size_t)(b * 192 + ch)) * 4096;
    const float* wk = w + ch * 9;
    float acc = 0.f;
    #pragma unroll
    for (int ky = 0; ky < 3; ++ky)
        #pragma unroll
        for (int kx = 0; kx < 3; ++kx) {
            int yy = y + ky - 1, xx = x + kx - 1;
            if (yy >= 0 && yy < 64 && xx >= 0 && xx < 64)
                acc += wk[ky * 3 + kx] * src[yy * 64 + xx];
        }
    out[((size_t)(b * 192 + ch)) * 4096 + l] = acc;
}

// Final attention logits+softmax, one block per q-row. grid (768), 256 thr.
__global__ void attnF_row_kernel(const float* __restrict__ qn, const float* __restrict__ kn,
                                 const float* __restrict__ temp, float* __restrict__ AF) {
    int row = blockIdx.x;            // ((b*6+hh)*32 + c)
    int hh = (row >> 5) % 6, b = row / 192;
    int tid = threadIdx.x;
    const float* q = qn + ((size_t)(b * 192) + (row % 192)) * 4096;
    const float* kb = kn + ((size_t)(b * 192 + hh * 32)) * 4096;
    float acc[32];
    #pragma unroll
    for (int d = 0; d < 32; ++d) acc[d] = 0.f;
    for (int i = tid; i < 4096; i += 256) {
        float qv = q[i];
        #pragma unroll
        for (int d = 0; d < 32; ++d) acc[d] += qv * kb[(size_t)d * 4096 + i];
    }
    #pragma unroll
    for (int d = 0; d < 32; ++d) {
        acc[d] += __shfl_xor(acc[d], 32);
        acc[d] += __shfl_xor(acc[d], 16);
        acc[d] += __shfl_xor(acc[d], 8);
        acc[d] += __shfl_xor(acc[d], 4);
        acc[d] += __shfl_xor(acc[d], 2);
        acc[d] += __shfl_xor(acc[d], 1);
    }
    __shared__ float red[4][32];
    int wid = tid >> 6, lane = tid & 63;
    if (lane == 0) {
        #pragma unroll
        for (int d = 0; d < 32; ++d) red[wid][d] = acc[d];
    }
    __syncthreads();
    if (tid < 32) {
        float s = red[0][tid] + red[1][tid] + red[2][tid] + red[3][tid];
        s *= temp[hh];
        float mx = s;
        mx = fmaxf(mx, __shfl_xor(mx, 16));
        mx = fmaxf(mx, __shfl_xor(mx, 8));
        mx = fmaxf(mx, __shfl_xor(mx, 4));
        mx = fmaxf(mx, __shfl_xor(mx, 2));
        mx = fmaxf(mx, __shfl_xor(mx, 1));
        float e = expf(s - mx);
        float sum = e;
        sum += __shfl_xor(sum, 16);
        sum += __shfl_xor(sum, 8);
        sum += __shfl_xor(sum, 4);
        sum += __shfl_xor(sum, 2);
        sum += __shfl_xor(sum, 1);
        AF[(size_t)row * 32 + tid] = e / sum;
    }
}

__global__ void attnF_out_kernel(const float* __restrict__ AF, const float* __restrict__ v,
                                 float* __restrict__ out) {
    int l = blockIdx.x * 256 + threadIdx.x;
    int ch = blockIdx.y, b = blockIdx.z;
    int hh = ch >> 5, c = ch & 31;
    const float* a = AF + ((size_t)((b * 6 + hh) * 32 + c)) * 32;
    const float* vp = v + ((size_t)(b * 192 + hh * 32)) * 4096 + l;
    float acc = 0.f;
    #pragma unroll
    for (int d = 0; d < 32; ++d) acc += a[d] * vp[(size_t)d * 4096];
    out[((size_t)(b * 192 + ch)) * 4096 + l] = acc;
}

// ---------------- launch ----------------
extern "C" void kernel_launch(void* const* d_in, const int* in_sizes, int n_in,
                              void* d_out, int out_size, void* d_ws, size_t ws_size,
                              hipStream_t stream) {
    const float* I    = (const float*)d_in[0];
    const float* T    = (const float*)d_in[1];
    const float* temp = (const float*)d_in[2];
    const float* ca1  = (const float*)d_in[3];
    const float* exow = (const float*)d_in[4];
    const float* exob = (const float*)d_in[5];
    const float* kvw  = (const float*)d_in[6];
    const float* kvdw = (const float*)d_in[7];
    const float* qdw  = (const float*)d_in[8];
    const float* projw= (const float*)d_in[9];
    ExPtrs ep;
    for (int j = 0; j < 12; ++j) {
        ep.w[j] = (const float*)d_in[10 + 2 * j];
        ep.b[j] = (const float*)d_in[11 + 2 * j];
    }

    // Arena (floats), ~69.4 MB:
    float* ws   = (float*)d_ws;
    float* AF   = ws;                       // 24576
    int*   idxb = (int*)(ws + 24576);       // 4
    float* R0   = ws + 32768;               // 3,145,728 (P1 during experts)
    float* R1   = R0 + 3145728;             // 3,145,728
    float* Ipad = R1 + 3145728;             // 3,551,232 (later: KN)
    float* Epad = Ipad + 3551232;           // 3,345,408 = 4*192*4356 (later: V)
    double* dsm = (double*)(Epad + 3345408);
    double* A64 = dsm;                      // 1536
    double* m64 = dsm + 1536;               // 64
    double* PA  = dsm + 1600;               // 24576 (stage-A partials)
    float* wtd  = (float*)(dsm + 26176);    // dense wt: 2,580,480
    size_t wtoff[6] = {0, 36864, 368640, 1290240, 1327104, 1658880};
    float* wtexo  = wtd + 2580480;          // 1,327,104
    float* wtkv   = wtexo + 1327104;        // 73,728
    float* wtproj = wtkv + 73728;           // 36,864
    double* xpool64 = (double*)R0;               // 196,608 d
    double* qn64    = (double*)(R0 + 393216);    // 786,432 d
    double* aout64  = (double*)R1;               // 786,432 d
    double* fm64    = (double*)(R1 + 1572864);   // 786,432 d
    float* KN = Ipad;
    float* V  = Epad;
    float* P1 = R0;
    DPtrs dp;
    for (int j = 0; j < 6; ++j) { dp.wt[j] = wtd + wtoff[j]; dp.bias[j] = ep.b[j]; }
    float* out  = (float*)d_out;

    dim3 g(16, 192, 4), gs8(4, 24, 4), gsplit8(4, 24, 8);

    // ---- weight transposes + input padding ----
    for (int j = 0; j < 6; ++j) {
        int KK = 1 + 2 * (j % 3);
        wtr8_kernel<<<512, 256, 0, stream>>>(ep.w[j], wtd + wtoff[j], 24, 192, KK * KK);
    }
    wtr8_kernel<<<1024, 256, 0, stream>>>(exow, wtexo, 24, 768, 9);
    wtr8_kernel<<<256, 256, 0, stream>>>(kvw, wtkv, 48, 192, 1);
    wtr8_kernel<<<256, 256, 0, stream>>>(projw, wtproj, 24, 192, 1);
    padfill_kernel<<<2048, 256, 0, stream>>>(I, Ipad);
    zero_kernel<<<2048, 256, 0, stream>>>(Epad, 3345408);

    // ---- Routing chain (b=0, f64) ----
    pool64_kernel<<<48, 256, 0, stream>>>(T, xpool64);
    norm64_f32_kernel<<<192, 256, 0, stream>>>(I, qn64);
    norm64_f64_kernel<<<48, 256, 0, stream>>>(xpool64);
    attnA64p_kernel<<<dim3(6, 16), 256, 0, stream>>>(qn64, xpool64, PA);
    attnA64r_kernel<<<6, 256, 0, stream>>>(PA, A64);
    aout64_kernel<<<dim3(16, 192), 256, 0, stream>>>(A64, xpool64, aout64);
    fm64_kernel<<<dim3(16, 192), 256, 0, stream>>>(aout64, ca1, fm64);
    meanx64_kernel<<<64, 256, 0, stream>>>(fm64, m64);
    route64_kernel<<<1, 64, 0, stream>>>(m64, idxb);

    // ---- Experts (8oc, ic-split x2): E in Epad, partials in P1(R0), fmap2 in R1 ----
    for (int s = 0; s < 4; ++s) {
        dense_sw_kernel<1><<<gsplit8, 256, 0, stream>>>(Ipad, dp, idxb, s, Epad, P1);
        dense_sw_kernel<3><<<gsplit8, 256, 0, stream>>>(Ipad, dp, idxb, s, Epad, P1);
        dense_sw_kernel<5><<<gsplit8, 256, 0, stream>>>(Ipad, dp, idxb, s, Epad, P1);
        expert_dw_kernel<<<g, 256, 0, stream>>>(I, ep, idxb, s, Epad);
        dense_combine_kernel<<<g, 256, 0, stream>>>(idxb, s, P1, Epad);
        exout_sw_kernel<<<gsplit8, 256, 0, stream>>>(Epad, wtexo, exob, R1, s, P1);
        exout_combine_kernel<<<g, 256, 0, stream>>>(P1, R1);
    }

    // ---- kv k-half (Ipad dead -> KN) ----
    conv1x1_sw_kernel<<<gs8, 256, 0, stream>>>(R1, wtkv, R0);
    dwconv_kernel<<<g, 256, 0, stream>>>(R0, kvdw, KN);
    rownorm_kernel<<<768, 256, 0, stream>>>(KN, KN);             // kn
    // ---- q ----
    dwconv_kernel<<<g, 256, 0, stream>>>(R1, qdw, R0);
    rownorm_kernel<<<768, 256, 0, stream>>>(R0, R0);             // qn
    attnF_row_kernel<<<768, 256, 0, stream>>>(R0, KN, temp, AF);
    // ---- kv v-half (Epad dead -> V) ----
    conv1x1_sw_kernel<<<gs8, 256, 0, stream>>>(R1, wtkv + 36864, R0);
    dwconv_kernel<<<g, 256, 0, stream>>>(R0, kvdw + 192 * 9, V);

    attnF_out_kernel<<<g, 256, 0, stream>>>(AF, V, R0);
    conv1x1_sw_kernel<<<gs8, 256, 0, stream>>>(R0, wtproj, out);
}